// Round 1
// baseline (1811.136 us; speedup 1.0000x reference)
//
#include <hip/hip_runtime.h>
#include <hip/hip_bf16.h>

#define NP_ 1500000
#define NV_ 1200000
#define S_  50000
#define E_  1600000

// ---------------- CSR build ----------------

__global__ void k_zero(int* a, int* b, int* c, int* d, int n) {
    int i = blockIdx.x * blockDim.x + threadIdx.x;
    if (i < n) { a[i] = 0; b[i] = 0; c[i] = 0; d[i] = 0; }
}

__global__ void k_hist(const int* __restrict__ seg, int* __restrict__ cnt, int n) {
    int i = blockIdx.x * blockDim.x + threadIdx.x;
    if (i < n) atomicAdd(&cnt[seg[i]], 1);
}

// exclusive scan over n ints (single block, 1024 threads); start[n] = total
__global__ void k_scan(const int* __restrict__ cnt, int* __restrict__ start, int n) {
    __shared__ int sums[1024];
    int t = threadIdx.x;
    int chunk = (n + 1023) / 1024;
    int lo = t * chunk;
    int hi = lo + chunk; if (hi > n) hi = n;
    int s = 0;
    for (int i = lo; i < hi; i++) s += cnt[i];
    sums[t] = s;
    __syncthreads();
    for (int off = 1; off < 1024; off <<= 1) {
        int v = (t >= off) ? sums[t - off] : 0;
        __syncthreads();
        sums[t] += v;
        __syncthreads();
    }
    int run = sums[t] - s;  // exclusive prefix
    for (int i = lo; i < hi; i++) { start[i] = run; run += cnt[i]; }
    if (t == 1023) start[n] = run;
}

__global__ void k_fill(const int* __restrict__ seg, const int* __restrict__ start,
                       int* __restrict__ cursor, int* __restrict__ list, int n) {
    int i = blockIdx.x * blockDim.x + threadIdx.x;
    if (i < n) {
        int s = seg[i];
        int off = atomicAdd(&cursor[s], 1);
        list[start[s] + off] = i;
    }
}

// ---------------- point semantic head: gather + 32->32 BN ReLU ->20 ----------------

__global__ __launch_bounds__(256) void k_point_head(
    const float* __restrict__ feats, const int* __restrict__ imap,
    const float* __restrict__ W1, const float* __restrict__ b1,
    const float* __restrict__ g, const float* __restrict__ be,
    const float* __restrict__ W2, const float* __restrict__ b2,
    float* __restrict__ out, int n)
{
    __shared__ float W1L[32 * 32], W2L[20 * 32], b1L[32], sL[32], beL[32], b2L[20];
    int tid = threadIdx.x;
    for (int idx = tid; idx < 1024; idx += 256) W1L[idx] = W1[idx];
    for (int idx = tid; idx < 640;  idx += 256) W2L[idx] = W2[idx];
    if (tid < 32) { b1L[tid] = b1[tid]; sL[tid] = g[tid] * rsqrtf(1.0001f); beL[tid] = be[tid]; }
    if (tid < 20) b2L[tid] = b2[tid];
    __syncthreads();
    int p = blockIdx.x * 256 + tid;
    if (p >= n) return;
    const float4* src = (const float4*)(feats + (size_t)imap[p] * 32);
    float x[32];
    #pragma unroll
    for (int i = 0; i < 8; i++) {
        float4 t = src[i];
        x[i * 4] = t.x; x[i * 4 + 1] = t.y; x[i * 4 + 2] = t.z; x[i * 4 + 3] = t.w;
    }
    float h[32];
    #pragma unroll
    for (int j = 0; j < 32; j++) {
        float a = b1L[j];
        #pragma unroll
        for (int i = 0; i < 32; i++) a += x[i] * W1L[j * 32 + i];
        a = a * sL[j] + beL[j];
        h[j] = a > 0.0f ? a : 0.0f;
    }
    float4 o4[5];
    float* o = (float*)o4;
    #pragma unroll
    for (int c = 0; c < 20; c++) {
        float a = b2L[c];
        #pragma unroll
        for (int j = 0; j < 32; j++) a += h[j] * W2L[c * 32 + j];
        o[c] = a;
    }
    float4* dst = (float4*)(out + (size_t)p * 20);
    #pragma unroll
    for (int i = 0; i < 5; i++) dst[i] = o4[i];
}

// ---------------- segment mean via CSR (half-wave = 32 dims per superpoint) ----------------

__global__ __launch_bounds__(256) void k_mean(
    const float* __restrict__ feats, const int* __restrict__ imap,
    const int* __restrict__ start, const int* __restrict__ list,
    float* __restrict__ emb)
{
    int t = blockIdx.x * 256 + threadIdx.x;
    int s = t >> 5, d = t & 31;
    if (s >= S_) return;
    int beg = start[s], end = start[s + 1];
    float acc = 0.0f;
    for (int i = beg; i < end; i++) {
        int p = list[i];
        acc += feats[(size_t)imap[p] * 32 + d];
    }
    float c = (float)(end - beg);
    emb[(size_t)s * 32 + d] = acc / fmaxf(c, 1.0f);
}

// ---------------- ecc = emb @ W_ecc.T  (wave per s, lane = out dim) ----------------

__global__ __launch_bounds__(256) void k_ecc(
    const float* __restrict__ emb, const float* __restrict__ Wecc, float* __restrict__ ecc)
{
    __shared__ float WL[64 * 33];
    int tid = threadIdx.x;
    for (int idx = tid; idx < 64 * 32; idx += 256) WL[(idx >> 5) * 33 + (idx & 31)] = Wecc[idx];
    __syncthreads();
    int t = blockIdx.x * 256 + tid;
    int s = t >> 6, j = t & 63;
    if (s >= S_) return;
    const float* x = emb + (size_t)s * 32;
    float a = 0.0f;
    #pragma unroll
    for (int i = 0; i < 32; i++) a += x[i] * WL[j * 33 + i];
    ecc[(size_t)s * 64 + j] = a;
}

// ---------------- q,k,v projections (wave per s) ----------------

__global__ __launch_bounds__(256) void k_qkv(
    const float* __restrict__ ecc,
    const float* __restrict__ Wq, const float* __restrict__ Wk, const float* __restrict__ Wv,
    float* __restrict__ q, float* __restrict__ k, float* __restrict__ v)
{
    __shared__ float QL[64 * 65], KL[64 * 65], VL[64 * 65];
    int tid = threadIdx.x;
    for (int idx = tid; idx < 4096; idx += 256) {
        int r = idx >> 6, c = idx & 63;
        QL[r * 65 + c] = Wq[idx]; KL[r * 65 + c] = Wk[idx]; VL[r * 65 + c] = Wv[idx];
    }
    __syncthreads();
    int t = blockIdx.x * 256 + tid;
    int s = t >> 6, j = t & 63;
    if (s >= S_) return;
    const float* x = ecc + (size_t)s * 64;
    float aq = 0.0f, ak = 0.0f, av = 0.0f;
    #pragma unroll
    for (int i = 0; i < 64; i++) {
        float xi = x[i];
        aq += xi * QL[j * 65 + i];
        ak += xi * KL[j * 65 + i];
        av += xi * VL[j * 65 + i];
    }
    q[(size_t)s * 64 + j] = aq;
    k[(size_t)s * 64 + j] = ak;
    v[(size_t)s * 64 + j] = av;
}

// ---------------- generic 64->64 BN ReLU -> C head (wave per s) ----------------

__global__ __launch_bounds__(256) void k_head(
    const float* __restrict__ in,
    const float* __restrict__ W1, const float* __restrict__ b1,
    const float* __restrict__ g, const float* __restrict__ be,
    const float* __restrict__ W2, const float* __restrict__ b2,
    float* __restrict__ out, int C)
{
    __shared__ float W1L[64 * 65];
    __shared__ float W2L[20 * 65];
    __shared__ float b1L[64], sL[64], beL[64], b2L[20];
    __shared__ float hbuf[4][64];
    int tid = threadIdx.x;
    for (int idx = tid; idx < 4096; idx += 256) W1L[(idx >> 6) * 65 + (idx & 63)] = W1[idx];
    for (int idx = tid; idx < C * 64; idx += 256) W2L[(idx >> 6) * 65 + (idx & 63)] = W2[idx];
    if (tid < 64) { b1L[tid] = b1[tid]; sL[tid] = g[tid] * rsqrtf(1.0001f); beL[tid] = be[tid]; }
    if (tid < C) b2L[tid] = b2[tid];
    __syncthreads();
    int w = tid >> 6, lane = tid & 63;
    int s = blockIdx.x * 4 + w;
    bool act = s < S_;
    float h = 0.0f;
    if (act) {
        const float* x = in + (size_t)s * 64;
        float a = b1L[lane];
        #pragma unroll
        for (int i = 0; i < 64; i++) a += x[i] * W1L[lane * 65 + i];
        a = a * sL[lane] + beL[lane];
        h = a > 0.0f ? a : 0.0f;
    }
    hbuf[w][lane] = h;
    __syncthreads();
    if (act && lane < C) {
        float a = b2L[lane];
        #pragma unroll
        for (int j = 0; j < 64; j++) a += hbuf[w][j] * W2L[lane * 65 + j];
        out[(size_t)s * C + lane] = a;
    }
}

// ---------------- per-edge: pos MLP + affinity ----------------

__global__ __launch_bounds__(256) void k_edge_aff(
    const int* __restrict__ eu, const int* __restrict__ ev,
    const float* __restrict__ ctr,
    const float* __restrict__ q, const float* __restrict__ k,
    const float* __restrict__ pw1, const float* __restrict__ pb1,
    const float* __restrict__ pw2, const float* __restrict__ pb2,
    float* __restrict__ aff)
{
    __shared__ float PW1[48], PB1[16], PW2[16];
    __shared__ float PB2;
    int tid = threadIdx.x;
    if (tid < 48) PW1[tid] = pw1[tid];
    if (tid < 16) { PB1[tid] = pb1[tid]; PW2[tid] = pw2[tid]; }
    if (tid == 0) PB2 = pb2[0];
    __syncthreads();
    int e = blockIdx.x * 256 + tid;
    if (e >= E_) return;
    int u = eu[e], w = ev[e];
    float dx = ctr[u * 3]     - ctr[w * 3];
    float dy = ctr[u * 3 + 1] - ctr[w * 3 + 1];
    float dz = ctr[u * 3 + 2] - ctr[w * 3 + 2];
    float pos = PB2;
    #pragma unroll
    for (int hh = 0; hh < 16; hh++) {
        float a = PB1[hh] + dx * PW1[hh * 3] + dy * PW1[hh * 3 + 1] + dz * PW1[hh * 3 + 2];
        pos += (a > 0.0f ? a : 0.0f) * PW2[hh];
    }
    const float4* qr = (const float4*)(q + (size_t)u * 64);
    const float4* kr = (const float4*)(k + (size_t)w * 64);
    float dot = 0.0f;
    #pragma unroll
    for (int i = 0; i < 16; i++) {
        float4 a = qr[i], b = kr[i];
        dot += a.x * b.x + a.y * b.y + a.z * b.z + a.w * b.w;
    }
    aff[e] = dot * 0.125f * pos;
}

// ---------------- segment softmax + weighted scatter of v (wave per s, lane = dim) ----------------

__global__ __launch_bounds__(256) void k_attn(
    const int* __restrict__ start, const int* __restrict__ list,
    const int* __restrict__ ev,
    const float* __restrict__ aff, const float* __restrict__ v,
    const float* __restrict__ ecc,
    float* __restrict__ soft, float* __restrict__ featb)
{
    int t = blockIdx.x * 256 + threadIdx.x;
    int s = t >> 6, lane = t & 63;
    if (s >= S_) return;
    int beg = start[s], end = start[s + 1];
    float m = -3.0e38f;
    for (int i = beg + lane; i < end; i += 64) m = fmaxf(m, aff[list[i]]);
    #pragma unroll
    for (int o = 32; o; o >>= 1) m = fmaxf(m, __shfl_xor(m, o, 64));
    float tot = 0.0f;
    for (int i = beg + lane; i < end; i += 64) tot += __expf(aff[list[i]] - m);
    #pragma unroll
    for (int o = 32; o; o >>= 1) tot += __shfl_xor(tot, o, 64);
    float inv = tot > 0.0f ? 1.0f / tot : 0.0f;
    float r = 0.0f;
    for (int i = beg; i < end; i++) {
        int e = list[i];
        float sf = __expf(aff[e] - m) * inv;
        r += sf * v[(size_t)ev[e] * 64 + lane];
        if (lane == 0) soft[e] = sf;
    }
    featb[(size_t)s * 64 + lane] = ecc[(size_t)s * 64 + lane] + r;
}

// ---------------- launch ----------------

extern "C" void kernel_launch(void* const* d_in, const int* in_sizes, int n_in,
                              void* d_out, int out_size, void* d_ws, size_t ws_size,
                              hipStream_t stream) {
    const float* output_feats = (const float*)d_in[0];
    const int*   input_map    = (const int*)d_in[1];
    const int*   superpoint   = (const int*)d_in[2];
    const float* ctr          = (const float*)d_in[3];
    const int*   edge_u       = (const int*)d_in[4];
    const int*   edge_v       = (const int*)d_in[5];
    const float* W_ecc        = (const float*)d_in[6];
    // heads: lin(7), ssem(13), soff(19), socc(25), ssize(31), feat(37); each W1,b1,g,be,W2,b2
    const float* lin_W1 = (const float*)d_in[7];
    const float* lin_b1 = (const float*)d_in[8];
    const float* lin_g  = (const float*)d_in[9];
    const float* lin_be = (const float*)d_in[10];
    const float* lin_W2 = (const float*)d_in[11];
    const float* lin_b2 = (const float*)d_in[12];
    const float* pos_W1 = (const float*)d_in[43];
    const float* pos_b1 = (const float*)d_in[44];
    const float* pos_W2 = (const float*)d_in[45];
    const float* pos_b2 = (const float*)d_in[46];
    const float* Wq     = (const float*)d_in[47];
    const float* Wk     = (const float*)d_in[48];
    const float* Wv     = (const float*)d_in[49];

    float* out = (float*)d_out;
    float* o_sem    = out;                    // [NP,20]
    float* o_spsem  = out + 30000000;         // [S,20]
    float* o_spoff  = out + 31000000;         // [S,3]
    float* o_spocc  = out + 31150000;         // [S]
    float* o_spsize = out + 31200000;         // [S]
    float* o_soft   = out + 31250000;         // [E]
    float* o_spdisc = out + 32850000;         // [S,7]

    // workspace layout
    char* base = (char*)d_ws;
    size_t off = 0;
    auto alloc = [&](size_t bytes) -> char* {
        char* p = base + off;
        off = (off + bytes + 255) & ~(size_t)255;
        return p;
    };
    int*   pt_cnt   = (int*)alloc(S_ * 4);
    int*   pt_start = (int*)alloc((S_ + 1) * 4);
    int*   pt_cur   = (int*)alloc(S_ * 4);
    int*   pt_list  = (int*)alloc((size_t)NP_ * 4);
    int*   e_cnt    = (int*)alloc(S_ * 4);
    int*   e_start  = (int*)alloc((S_ + 1) * 4);
    int*   e_cur    = (int*)alloc(S_ * 4);
    int*   e_list   = (int*)alloc((size_t)E_ * 4);
    float* emb      = (float*)alloc((size_t)S_ * 32 * 4);
    float* ecc      = (float*)alloc((size_t)S_ * 64 * 4);
    float* qb       = (float*)alloc((size_t)S_ * 64 * 4);
    float* kb       = (float*)alloc((size_t)S_ * 64 * 4);
    float* vb       = (float*)alloc((size_t)S_ * 64 * 4);
    float* aff      = (float*)alloc((size_t)E_ * 4);
    float* featb    = qb;  // reuse q buffer after edge pass A

    // 1. zero counters
    k_zero<<<(S_ + 255) / 256, 256, 0, stream>>>(pt_cnt, pt_cur, e_cnt, e_cur, S_);
    // 2. histograms
    k_hist<<<(NP_ + 255) / 256, 256, 0, stream>>>(superpoint, pt_cnt, NP_);
    k_hist<<<(E_ + 255) / 256, 256, 0, stream>>>(edge_u, e_cnt, E_);
    // 3. scans
    k_scan<<<1, 1024, 0, stream>>>(pt_cnt, pt_start, S_);
    k_scan<<<1, 1024, 0, stream>>>(e_cnt, e_start, S_);
    // 4. fill CSR lists
    k_fill<<<(NP_ + 255) / 256, 256, 0, stream>>>(superpoint, pt_start, pt_cur, pt_list, NP_);
    k_fill<<<(E_ + 255) / 256, 256, 0, stream>>>(edge_u, e_start, e_cur, e_list, E_);
    // 5. point semantic head
    k_point_head<<<(NP_ + 255) / 256, 256, 0, stream>>>(
        output_feats, input_map, lin_W1, lin_b1, lin_g, lin_be, lin_W2, lin_b2, o_sem, NP_);
    // 6. segment mean
    k_mean<<<(S_ * 32) / 256, 256, 0, stream>>>(output_feats, input_map, pt_start, pt_list, emb);
    // 7. ecc projection
    k_ecc<<<S_ / 4, 256, 0, stream>>>(emb, W_ecc, ecc);
    // 8. q,k,v
    k_qkv<<<S_ / 4, 256, 0, stream>>>(ecc, Wq, Wk, Wv, qb, kb, vb);
    // 9. four heads on ecc
    k_head<<<S_ / 4, 256, 0, stream>>>(ecc, (const float*)d_in[13], (const float*)d_in[14],
        (const float*)d_in[15], (const float*)d_in[16], (const float*)d_in[17], (const float*)d_in[18],
        o_spsem, 20);
    k_head<<<S_ / 4, 256, 0, stream>>>(ecc, (const float*)d_in[19], (const float*)d_in[20],
        (const float*)d_in[21], (const float*)d_in[22], (const float*)d_in[23], (const float*)d_in[24],
        o_spoff, 3);
    k_head<<<S_ / 4, 256, 0, stream>>>(ecc, (const float*)d_in[25], (const float*)d_in[26],
        (const float*)d_in[27], (const float*)d_in[28], (const float*)d_in[29], (const float*)d_in[30],
        o_spocc, 1);
    k_head<<<S_ / 4, 256, 0, stream>>>(ecc, (const float*)d_in[31], (const float*)d_in[32],
        (const float*)d_in[33], (const float*)d_in[34], (const float*)d_in[35], (const float*)d_in[36],
        o_spsize, 1);
    // 10. edge affinity
    k_edge_aff<<<(E_ + 255) / 256, 256, 0, stream>>>(
        edge_u, edge_v, ctr, qb, kb, pos_W1, pos_b1, pos_W2, pos_b2, aff);
    // 11. segment softmax + res accumulation (featb overlays qb — safe after pass 10)
    k_attn<<<S_ / 4, 256, 0, stream>>>(e_start, e_list, edge_v, aff, vb, ecc, o_soft, featb);
    // 12. feat head on ecc + res
    k_head<<<S_ / 4, 256, 0, stream>>>(featb, (const float*)d_in[37], (const float*)d_in[38],
        (const float*)d_in[39], (const float*)d_in[40], (const float*)d_in[41], (const float*)d_in[42],
        o_spdisc, 7);
}

// Round 2
// 1594.178 us; speedup vs baseline: 1.1361x; 1.1361x over previous
//
#include <hip/hip_runtime.h>
#include <hip/hip_bf16.h>

#define NP_ 1500000
#define NV_ 1200000
#define S_  50000
#define E_  1600000

// ---------------- CSR build ----------------

__global__ void k_zero(int* a, int* b, int* c, int* d, int n) {
    int i = blockIdx.x * blockDim.x + threadIdx.x;
    if (i < n) { a[i] = 0; b[i] = 0; c[i] = 0; d[i] = 0; }
}

__global__ void k_hist(const int* __restrict__ seg, int* __restrict__ cnt, int n) {
    int i = blockIdx.x * blockDim.x + threadIdx.x;
    if (i < n) atomicAdd(&cnt[seg[i]], 1);
}

// exclusive scan over n ints (single block, 1024 threads); start[n] = total
__global__ void k_scan(const int* __restrict__ cnt, int* __restrict__ start, int n) {
    __shared__ int sums[1024];
    int t = threadIdx.x;
    int chunk = (n + 1023) / 1024;
    int lo = t * chunk;
    int hi = lo + chunk; if (hi > n) hi = n;
    int s = 0;
    for (int i = lo; i < hi; i++) s += cnt[i];
    sums[t] = s;
    __syncthreads();
    for (int off = 1; off < 1024; off <<= 1) {
        int v = (t >= off) ? sums[t - off] : 0;
        __syncthreads();
        sums[t] += v;
        __syncthreads();
    }
    int run = sums[t] - s;  // exclusive prefix
    for (int i = lo; i < hi; i++) { start[i] = run; run += cnt[i]; }
    if (t == 1023) start[n] = run;
}

// points: store voxel index (imap[p]) directly in CSR order — kills one gather level in k_mean
__global__ void k_fill_pts(const int* __restrict__ seg, const int* __restrict__ imap,
                           const int* __restrict__ start, int* __restrict__ cursor,
                           int* __restrict__ vidx, int n) {
    int i = blockIdx.x * blockDim.x + threadIdx.x;
    if (i < n) {
        int s = seg[i];
        int off = atomicAdd(&cursor[s], 1);
        vidx[start[s] + off] = imap[i];
    }
}

// edges: store ev and original edge id in CSR order; record rank[e] for scatter of aff
__global__ void k_fill_edges(const int* __restrict__ eu, const int* __restrict__ ev,
                             const int* __restrict__ start, int* __restrict__ cursor,
                             int* __restrict__ list, int* __restrict__ evs,
                             int* __restrict__ rank, int n) {
    int i = blockIdx.x * blockDim.x + threadIdx.x;
    if (i < n) {
        int s = eu[i];
        int off = atomicAdd(&cursor[s], 1);
        int r = start[s] + off;
        list[r] = i;
        evs[r]  = ev[i];
        rank[i] = r;
    }
}

// ---------------- point semantic head: gather + 32->32 BN ReLU ->20 ----------------

__global__ __launch_bounds__(256) void k_point_head(
    const float* __restrict__ feats, const int* __restrict__ imap,
    const float* __restrict__ W1, const float* __restrict__ b1,
    const float* __restrict__ g, const float* __restrict__ be,
    const float* __restrict__ W2, const float* __restrict__ b2,
    float* __restrict__ out, int n)
{
    __shared__ float W1L[32 * 32], W2L[20 * 32], b1L[32], sL[32], beL[32], b2L[20];
    int tid = threadIdx.x;
    for (int idx = tid; idx < 1024; idx += 256) W1L[idx] = W1[idx];
    for (int idx = tid; idx < 640;  idx += 256) W2L[idx] = W2[idx];
    if (tid < 32) { b1L[tid] = b1[tid]; sL[tid] = g[tid] * rsqrtf(1.0001f); beL[tid] = be[tid]; }
    if (tid < 20) b2L[tid] = b2[tid];
    __syncthreads();
    int p = blockIdx.x * 256 + tid;
    if (p >= n) return;
    const float4* src = (const float4*)(feats + (size_t)imap[p] * 32);
    float x[32];
    #pragma unroll
    for (int i = 0; i < 8; i++) {
        float4 t = src[i];
        x[i * 4] = t.x; x[i * 4 + 1] = t.y; x[i * 4 + 2] = t.z; x[i * 4 + 3] = t.w;
    }
    float h[32];
    #pragma unroll
    for (int j = 0; j < 32; j++) {
        float a = b1L[j];
        #pragma unroll
        for (int i = 0; i < 32; i++) a += x[i] * W1L[j * 32 + i];
        a = a * sL[j] + beL[j];
        h[j] = a > 0.0f ? a : 0.0f;
    }
    float4 o4[5];
    float* o = (float*)o4;
    #pragma unroll
    for (int c = 0; c < 20; c++) {
        float a = b2L[c];
        #pragma unroll
        for (int j = 0; j < 32; j++) a += h[j] * W2L[c * 32 + j];
        o[c] = a;
    }
    float4* dst = (float4*)(out + (size_t)p * 20);
    #pragma unroll
    for (int i = 0; i < 5; i++) dst[i] = o4[i];
}

// ---------------- segment mean via CSR (half-wave = 32 dims per superpoint) ----------------

__global__ __launch_bounds__(256) void k_mean(
    const float* __restrict__ feats, const int* __restrict__ vidx,
    const int* __restrict__ start, float* __restrict__ emb)
{
    int t = blockIdx.x * 256 + threadIdx.x;
    int s = t >> 5, d = t & 31;
    if (s >= S_) return;
    int beg = start[s], end = start[s + 1];
    float acc = 0.0f;
    int i = beg;
    for (; i + 4 <= end; i += 4) {
        int p0 = vidx[i], p1 = vidx[i + 1], p2 = vidx[i + 2], p3 = vidx[i + 3];
        float f0 = feats[(size_t)p0 * 32 + d];
        float f1 = feats[(size_t)p1 * 32 + d];
        float f2 = feats[(size_t)p2 * 32 + d];
        float f3 = feats[(size_t)p3 * 32 + d];
        acc += f0 + f1 + f2 + f3;
    }
    for (; i < end; i++) acc += feats[(size_t)vidx[i] * 32 + d];
    float c = (float)(end - beg);
    emb[(size_t)s * 32 + d] = acc / fmaxf(c, 1.0f);
}

// ---------------- ecc = emb @ W_ecc.T  (wave per s, lane = out dim) ----------------

__global__ __launch_bounds__(256) void k_ecc(
    const float* __restrict__ emb, const float* __restrict__ Wecc, float* __restrict__ ecc)
{
    __shared__ float WL[64 * 33];
    int tid = threadIdx.x;
    for (int idx = tid; idx < 64 * 32; idx += 256) WL[(idx >> 5) * 33 + (idx & 31)] = Wecc[idx];
    __syncthreads();
    int t = blockIdx.x * 256 + tid;
    int s = t >> 6, j = t & 63;
    if (s >= S_) return;
    const float* x = emb + (size_t)s * 32;
    float a = 0.0f;
    #pragma unroll
    for (int i = 0; i < 32; i++) a += x[i] * WL[j * 33 + i];
    ecc[(size_t)s * 64 + j] = a;
}

// ---------------- q,k,v projections (wave per s) ----------------

__global__ __launch_bounds__(256) void k_qkv(
    const float* __restrict__ ecc,
    const float* __restrict__ Wq, const float* __restrict__ Wk, const float* __restrict__ Wv,
    float* __restrict__ q, float* __restrict__ k, float* __restrict__ v)
{
    __shared__ float QL[64 * 65], KL[64 * 65], VL[64 * 65];
    int tid = threadIdx.x;
    for (int idx = tid; idx < 4096; idx += 256) {
        int r = idx >> 6, c = idx & 63;
        QL[r * 65 + c] = Wq[idx]; KL[r * 65 + c] = Wk[idx]; VL[r * 65 + c] = Wv[idx];
    }
    __syncthreads();
    int t = blockIdx.x * 256 + tid;
    int s = t >> 6, j = t & 63;
    if (s >= S_) return;
    const float* x = ecc + (size_t)s * 64;
    float aq = 0.0f, ak = 0.0f, av = 0.0f;
    #pragma unroll
    for (int i = 0; i < 64; i++) {
        float xi = x[i];
        aq += xi * QL[j * 65 + i];
        ak += xi * KL[j * 65 + i];
        av += xi * VL[j * 65 + i];
    }
    q[(size_t)s * 64 + j] = aq;
    k[(size_t)s * 64 + j] = ak;
    v[(size_t)s * 64 + j] = av;
}

// ---------------- generic 64->64 BN ReLU -> C head (wave per s) ----------------

__global__ __launch_bounds__(256) void k_head(
    const float* __restrict__ in,
    const float* __restrict__ W1, const float* __restrict__ b1,
    const float* __restrict__ g, const float* __restrict__ be,
    const float* __restrict__ W2, const float* __restrict__ b2,
    float* __restrict__ out, int C)
{
    __shared__ float W1L[64 * 65];
    __shared__ float W2L[20 * 65];
    __shared__ float b1L[64], sL[64], beL[64], b2L[20];
    __shared__ float hbuf[4][64];
    int tid = threadIdx.x;
    for (int idx = tid; idx < 4096; idx += 256) W1L[(idx >> 6) * 65 + (idx & 63)] = W1[idx];
    for (int idx = tid; idx < C * 64; idx += 256) W2L[(idx >> 6) * 65 + (idx & 63)] = W2[idx];
    if (tid < 64) { b1L[tid] = b1[tid]; sL[tid] = g[tid] * rsqrtf(1.0001f); beL[tid] = be[tid]; }
    if (tid < C) b2L[tid] = b2[tid];
    __syncthreads();
    int w = tid >> 6, lane = tid & 63;
    int s = blockIdx.x * 4 + w;
    bool act = s < S_;
    float h = 0.0f;
    if (act) {
        const float* x = in + (size_t)s * 64;
        float a = b1L[lane];
        #pragma unroll
        for (int i = 0; i < 64; i++) a += x[i] * W1L[lane * 65 + i];
        a = a * sL[lane] + beL[lane];
        h = a > 0.0f ? a : 0.0f;
    }
    hbuf[w][lane] = h;
    __syncthreads();
    if (act && lane < C) {
        float a = b2L[lane];
        #pragma unroll
        for (int j = 0; j < 64; j++) a += hbuf[w][j] * W2L[lane * 65 + j];
        out[(size_t)s * C + lane] = a;
    }
}

// ---------------- per-edge: pos MLP + affinity, scatter into CSR order ----------------

__global__ __launch_bounds__(256) void k_edge_aff(
    const int* __restrict__ eu, const int* __restrict__ ev,
    const int* __restrict__ rank,
    const float* __restrict__ ctr,
    const float* __restrict__ q, const float* __restrict__ k,
    const float* __restrict__ pw1, const float* __restrict__ pb1,
    const float* __restrict__ pw2, const float* __restrict__ pb2,
    float* __restrict__ affs)
{
    __shared__ float PW1[48], PB1[16], PW2[16];
    __shared__ float PB2;
    int tid = threadIdx.x;
    if (tid < 48) PW1[tid] = pw1[tid];
    if (tid < 16) { PB1[tid] = pb1[tid]; PW2[tid] = pw2[tid]; }
    if (tid == 0) PB2 = pb2[0];
    __syncthreads();
    int e = blockIdx.x * 256 + tid;
    if (e >= E_) return;
    int u = eu[e], w = ev[e];
    float dx = ctr[u * 3]     - ctr[w * 3];
    float dy = ctr[u * 3 + 1] - ctr[w * 3 + 1];
    float dz = ctr[u * 3 + 2] - ctr[w * 3 + 2];
    float pos = PB2;
    #pragma unroll
    for (int hh = 0; hh < 16; hh++) {
        float a = PB1[hh] + dx * PW1[hh * 3] + dy * PW1[hh * 3 + 1] + dz * PW1[hh * 3 + 2];
        pos += (a > 0.0f ? a : 0.0f) * PW2[hh];
    }
    const float4* qr = (const float4*)(q + (size_t)u * 64);
    const float4* kr = (const float4*)(k + (size_t)w * 64);
    float dot = 0.0f;
    #pragma unroll
    for (int i = 0; i < 16; i++) {
        float4 a = qr[i], b = kr[i];
        dot += a.x * b.x + a.y * b.y + a.z * b.z + a.w * b.w;
    }
    affs[rank[e]] = dot * 0.125f * pos;
}

// ---------------- segment softmax + weighted scatter of v (wave per s, lane = dim) ----------------
// affs/evs/list are in CSR order: phases 1-2 fully coalesced; res pass 4-way unrolled for MLP.

__global__ __launch_bounds__(256) void k_attn(
    const int* __restrict__ start, const int* __restrict__ list,
    const int* __restrict__ evs, const float* __restrict__ affs,
    const float* __restrict__ v, const float* __restrict__ ecc,
    float* __restrict__ soft, float* __restrict__ featb)
{
    int t = blockIdx.x * 256 + threadIdx.x;
    int s = t >> 6, lane = t & 63;
    if (s >= S_) return;
    int beg = start[s], end = start[s + 1];
    float m = -3.0e38f;
    for (int i = beg + lane; i < end; i += 64) m = fmaxf(m, affs[i]);
    #pragma unroll
    for (int o = 32; o; o >>= 1) m = fmaxf(m, __shfl_xor(m, o, 64));
    float tot = 0.0f;
    for (int i = beg + lane; i < end; i += 64) tot += __expf(affs[i] - m);
    #pragma unroll
    for (int o = 32; o; o >>= 1) tot += __shfl_xor(tot, o, 64);
    float inv = tot > 0.0f ? 1.0f / tot : 0.0f;
    float r = 0.0f;
    int i = beg;
    for (; i + 4 <= end; i += 4) {
        float a0 = affs[i], a1 = affs[i + 1], a2 = affs[i + 2], a3 = affs[i + 3];
        int   e0 = evs[i],  e1 = evs[i + 1],  e2 = evs[i + 2],  e3 = evs[i + 3];
        float s0 = __expf(a0 - m) * inv;
        float s1 = __expf(a1 - m) * inv;
        float s2 = __expf(a2 - m) * inv;
        float s3 = __expf(a3 - m) * inv;
        float v0 = v[(size_t)e0 * 64 + lane];
        float v1 = v[(size_t)e1 * 64 + lane];
        float v2 = v[(size_t)e2 * 64 + lane];
        float v3 = v[(size_t)e3 * 64 + lane];
        r += s0 * v0; r += s1 * v1; r += s2 * v2; r += s3 * v3;
        if (lane < 4) {
            float sv = lane == 0 ? s0 : lane == 1 ? s1 : lane == 2 ? s2 : s3;
            soft[list[i + lane]] = sv;
        }
    }
    for (; i < end; i++) {
        float sf = __expf(affs[i] - m) * inv;
        r += sf * v[(size_t)evs[i] * 64 + lane];
        if (lane == 0) soft[list[i]] = sf;
    }
    featb[(size_t)s * 64 + lane] = ecc[(size_t)s * 64 + lane] + r;
}

// ---------------- launch ----------------

extern "C" void kernel_launch(void* const* d_in, const int* in_sizes, int n_in,
                              void* d_out, int out_size, void* d_ws, size_t ws_size,
                              hipStream_t stream) {
    const float* output_feats = (const float*)d_in[0];
    const int*   input_map    = (const int*)d_in[1];
    const int*   superpoint   = (const int*)d_in[2];
    const float* ctr          = (const float*)d_in[3];
    const int*   edge_u       = (const int*)d_in[4];
    const int*   edge_v       = (const int*)d_in[5];
    const float* W_ecc        = (const float*)d_in[6];
    const float* lin_W1 = (const float*)d_in[7];
    const float* lin_b1 = (const float*)d_in[8];
    const float* lin_g  = (const float*)d_in[9];
    const float* lin_be = (const float*)d_in[10];
    const float* lin_W2 = (const float*)d_in[11];
    const float* lin_b2 = (const float*)d_in[12];
    const float* pos_W1 = (const float*)d_in[43];
    const float* pos_b1 = (const float*)d_in[44];
    const float* pos_W2 = (const float*)d_in[45];
    const float* pos_b2 = (const float*)d_in[46];
    const float* Wq     = (const float*)d_in[47];
    const float* Wk     = (const float*)d_in[48];
    const float* Wv     = (const float*)d_in[49];

    float* out = (float*)d_out;
    float* o_sem    = out;                    // [NP,20]
    float* o_spsem  = out + 30000000;         // [S,20]
    float* o_spoff  = out + 31000000;         // [S,3]
    float* o_spocc  = out + 31150000;         // [S]
    float* o_spsize = out + 31200000;         // [S]
    float* o_soft   = out + 31250000;         // [E]
    float* o_spdisc = out + 32850000;         // [S,7]

    // workspace layout
    char* base = (char*)d_ws;
    size_t off = 0;
    auto alloc = [&](size_t bytes) -> char* {
        char* p = base + off;
        off = (off + bytes + 255) & ~(size_t)255;
        return p;
    };
    int*   pt_cnt   = (int*)alloc(S_ * 4);
    int*   pt_start = (int*)alloc((S_ + 1) * 4);
    int*   pt_cur   = (int*)alloc(S_ * 4);
    int*   vidx     = (int*)alloc((size_t)NP_ * 4);
    int*   e_cnt    = (int*)alloc(S_ * 4);
    int*   e_start  = (int*)alloc((S_ + 1) * 4);
    int*   e_cur    = (int*)alloc(S_ * 4);
    int*   e_list   = (int*)alloc((size_t)E_ * 4);
    int*   e_vs     = (int*)alloc((size_t)E_ * 4);
    int*   e_rank   = (int*)alloc((size_t)E_ * 4);
    float* affs     = (float*)alloc((size_t)E_ * 4);
    float* emb      = (float*)alloc((size_t)S_ * 32 * 4);
    float* ecc      = (float*)alloc((size_t)S_ * 64 * 4);
    float* qb       = (float*)alloc((size_t)S_ * 64 * 4);
    float* kb       = (float*)alloc((size_t)S_ * 64 * 4);
    float* vb       = (float*)alloc((size_t)S_ * 64 * 4);
    float* featb    = qb;  // reuse q buffer after k_edge_aff

    k_zero<<<(S_ + 255) / 256, 256, 0, stream>>>(pt_cnt, pt_cur, e_cnt, e_cur, S_);
    k_hist<<<(NP_ + 255) / 256, 256, 0, stream>>>(superpoint, pt_cnt, NP_);
    k_hist<<<(E_ + 255) / 256, 256, 0, stream>>>(edge_u, e_cnt, E_);
    k_scan<<<1, 1024, 0, stream>>>(pt_cnt, pt_start, S_);
    k_scan<<<1, 1024, 0, stream>>>(e_cnt, e_start, S_);
    k_fill_pts<<<(NP_ + 255) / 256, 256, 0, stream>>>(superpoint, input_map, pt_start, pt_cur, vidx, NP_);
    k_fill_edges<<<(E_ + 255) / 256, 256, 0, stream>>>(edge_u, edge_v, e_start, e_cur, e_list, e_vs, e_rank, E_);
    k_point_head<<<(NP_ + 255) / 256, 256, 0, stream>>>(
        output_feats, input_map, lin_W1, lin_b1, lin_g, lin_be, lin_W2, lin_b2, o_sem, NP_);
    k_mean<<<(S_ * 32) / 256, 256, 0, stream>>>(output_feats, vidx, pt_start, emb);
    k_ecc<<<S_ / 4, 256, 0, stream>>>(emb, W_ecc, ecc);
    k_qkv<<<S_ / 4, 256, 0, stream>>>(ecc, Wq, Wk, Wv, qb, kb, vb);
    k_head<<<S_ / 4, 256, 0, stream>>>(ecc, (const float*)d_in[13], (const float*)d_in[14],
        (const float*)d_in[15], (const float*)d_in[16], (const float*)d_in[17], (const float*)d_in[18],
        o_spsem, 20);
    k_head<<<S_ / 4, 256, 0, stream>>>(ecc, (const float*)d_in[19], (const float*)d_in[20],
        (const float*)d_in[21], (const float*)d_in[22], (const float*)d_in[23], (const float*)d_in[24],
        o_spoff, 3);
    k_head<<<S_ / 4, 256, 0, stream>>>(ecc, (const float*)d_in[25], (const float*)d_in[26],
        (const float*)d_in[27], (const float*)d_in[28], (const float*)d_in[29], (const float*)d_in[30],
        o_spocc, 1);
    k_head<<<S_ / 4, 256, 0, stream>>>(ecc, (const float*)d_in[31], (const float*)d_in[32],
        (const float*)d_in[33], (const float*)d_in[34], (const float*)d_in[35], (const float*)d_in[36],
        o_spsize, 1);
    k_edge_aff<<<(E_ + 255) / 256, 256, 0, stream>>>(
        edge_u, edge_v, e_rank, ctr, qb, kb, pos_W1, pos_b1, pos_W2, pos_b2, affs);
    k_attn<<<S_ / 4, 256, 0, stream>>>(e_start, e_list, e_vs, affs, vb, ecc, o_soft, featb);
    k_head<<<S_ / 4, 256, 0, stream>>>(featb, (const float*)d_in[37], (const float*)d_in[38],
        (const float*)d_in[39], (const float*)d_in[40], (const float*)d_in[41], (const float*)d_in[42],
        o_spdisc, 7);
}

// Round 3
// 1516.878 us; speedup vs baseline: 1.1940x; 1.0510x over previous
//
#include <hip/hip_runtime.h>
#include <hip/hip_bf16.h>

#define NP_ 1500000
#define NV_ 1200000
#define S_  50000
#define E_  1600000

// ---------------- CSR build ----------------

__global__ void k_zero(int* a, int* b, int* c, int* d, int n) {
    int i = blockIdx.x * blockDim.x + threadIdx.x;
    if (i < n) { a[i] = 0; b[i] = 0; c[i] = 0; d[i] = 0; }
}

__global__ void k_hist(const int* __restrict__ seg, int* __restrict__ cnt, int n) {
    int i = blockIdx.x * blockDim.x + threadIdx.x;
    if (i < n) atomicAdd(&cnt[seg[i]], 1);
}

// exclusive scan over n ints (single block, 1024 threads); start[n] = total
__global__ void k_scan(const int* __restrict__ cnt, int* __restrict__ start, int n) {
    __shared__ int sums[1024];
    int t = threadIdx.x;
    int chunk = (n + 1023) / 1024;
    int lo = t * chunk;
    int hi = lo + chunk; if (hi > n) hi = n;
    int s = 0;
    for (int i = lo; i < hi; i++) s += cnt[i];
    sums[t] = s;
    __syncthreads();
    for (int off = 1; off < 1024; off <<= 1) {
        int v = (t >= off) ? sums[t - off] : 0;
        __syncthreads();
        sums[t] += v;
        __syncthreads();
    }
    int run = sums[t] - s;  // exclusive prefix
    for (int i = lo; i < hi; i++) { start[i] = run; run += cnt[i]; }
    if (t == 1023) start[n] = run;
}

// points: store voxel index (imap[p]) directly in CSR order
__global__ void k_fill_pts(const int* __restrict__ seg, const int* __restrict__ imap,
                           const int* __restrict__ start, int* __restrict__ cursor,
                           int* __restrict__ vidx, int n) {
    int i = blockIdx.x * blockDim.x + threadIdx.x;
    if (i < n) {
        int s = seg[i];
        int off = atomicAdd(&cursor[s], 1);
        vidx[start[s] + off] = imap[i];
    }
}

// edges: store ev and original edge id in CSR order; record rank[e] for scatter of pos
__global__ void k_fill_edges(const int* __restrict__ eu, const int* __restrict__ ev,
                             const int* __restrict__ start, int* __restrict__ cursor,
                             int* __restrict__ list, int* __restrict__ evs,
                             int* __restrict__ rank, int n) {
    int i = blockIdx.x * blockDim.x + threadIdx.x;
    if (i < n) {
        int s = eu[i];
        int off = atomicAdd(&cursor[s], 1);
        int r = start[s] + off;
        list[r] = i;
        evs[r]  = ev[i];
        rank[i] = r;
    }
}

// ---------------- point semantic head: gather + 32->32 BN ReLU ->20 ----------------

__global__ __launch_bounds__(256) void k_point_head(
    const float* __restrict__ feats, const int* __restrict__ imap,
    const float* __restrict__ W1, const float* __restrict__ b1,
    const float* __restrict__ g, const float* __restrict__ be,
    const float* __restrict__ W2, const float* __restrict__ b2,
    float* __restrict__ out, int n)
{
    __shared__ float W1L[32 * 32], W2L[20 * 32], b1L[32], sL[32], beL[32], b2L[20];
    int tid = threadIdx.x;
    for (int idx = tid; idx < 1024; idx += 256) W1L[idx] = W1[idx];
    for (int idx = tid; idx < 640;  idx += 256) W2L[idx] = W2[idx];
    if (tid < 32) { b1L[tid] = b1[tid]; sL[tid] = g[tid] * rsqrtf(1.0001f); beL[tid] = be[tid]; }
    if (tid < 20) b2L[tid] = b2[tid];
    __syncthreads();
    int p = blockIdx.x * 256 + tid;
    if (p >= n) return;
    const float4* src = (const float4*)(feats + (size_t)imap[p] * 32);
    float x[32];
    #pragma unroll
    for (int i = 0; i < 8; i++) {
        float4 t = src[i];
        x[i * 4] = t.x; x[i * 4 + 1] = t.y; x[i * 4 + 2] = t.z; x[i * 4 + 3] = t.w;
    }
    float h[32];
    #pragma unroll
    for (int j = 0; j < 32; j++) {
        float a = b1L[j];
        #pragma unroll
        for (int i = 0; i < 32; i++) a += x[i] * W1L[j * 32 + i];
        a = a * sL[j] + beL[j];
        h[j] = a > 0.0f ? a : 0.0f;
    }
    float4 o4[5];
    float* o = (float*)o4;
    #pragma unroll
    for (int c = 0; c < 20; c++) {
        float a = b2L[c];
        #pragma unroll
        for (int j = 0; j < 32; j++) a += h[j] * W2L[c * 32 + j];
        o[c] = a;
    }
    float4* dst = (float4*)(out + (size_t)p * 20);
    #pragma unroll
    for (int i = 0; i < 5; i++) dst[i] = o4[i];
}

// ---------------- segment mean via CSR (half-wave = 32 dims per superpoint) ----------------

__global__ __launch_bounds__(256) void k_mean(
    const float* __restrict__ feats, const int* __restrict__ vidx,
    const int* __restrict__ start, float* __restrict__ emb)
{
    int t = blockIdx.x * 256 + threadIdx.x;
    int s = t >> 5, d = t & 31;
    if (s >= S_) return;
    int beg = start[s], end = start[s + 1];
    float acc = 0.0f;
    int i = beg;
    for (; i + 4 <= end; i += 4) {
        int p0 = vidx[i], p1 = vidx[i + 1], p2 = vidx[i + 2], p3 = vidx[i + 3];
        float f0 = feats[(size_t)p0 * 32 + d];
        float f1 = feats[(size_t)p1 * 32 + d];
        float f2 = feats[(size_t)p2 * 32 + d];
        float f3 = feats[(size_t)p3 * 32 + d];
        acc += f0 + f1 + f2 + f3;
    }
    for (; i < end; i++) acc += feats[(size_t)vidx[i] * 32 + d];
    float c = (float)(end - beg);
    emb[(size_t)s * 32 + d] = acc / fmaxf(c, 1.0f);
}

// ---------------- ecc = emb @ W_ecc.T  (wave per s, lane = out dim) ----------------

__global__ __launch_bounds__(256) void k_ecc(
    const float* __restrict__ emb, const float* __restrict__ Wecc, float* __restrict__ ecc)
{
    __shared__ float WL[64 * 33];
    int tid = threadIdx.x;
    for (int idx = tid; idx < 64 * 32; idx += 256) WL[(idx >> 5) * 33 + (idx & 31)] = Wecc[idx];
    __syncthreads();
    int t = blockIdx.x * 256 + tid;
    int s = t >> 6, j = t & 63;
    if (s >= S_) return;
    const float* x = emb + (size_t)s * 32;
    float a = 0.0f;
    #pragma unroll
    for (int i = 0; i < 32; i++) a += x[i] * WL[j * 33 + i];
    ecc[(size_t)s * 64 + j] = a;
}

// ---------------- q,k,v projections (wave per s) ----------------

__global__ __launch_bounds__(256) void k_qkv(
    const float* __restrict__ ecc,
    const float* __restrict__ Wq, const float* __restrict__ Wk, const float* __restrict__ Wv,
    float* __restrict__ q, float* __restrict__ k, float* __restrict__ v)
{
    __shared__ float QL[64 * 65], KL[64 * 65], VL[64 * 65];
    int tid = threadIdx.x;
    for (int idx = tid; idx < 4096; idx += 256) {
        int r = idx >> 6, c = idx & 63;
        QL[r * 65 + c] = Wq[idx]; KL[r * 65 + c] = Wk[idx]; VL[r * 65 + c] = Wv[idx];
    }
    __syncthreads();
    int t = blockIdx.x * 256 + tid;
    int s = t >> 6, j = t & 63;
    if (s >= S_) return;
    const float* x = ecc + (size_t)s * 64;
    float aq = 0.0f, ak = 0.0f, av = 0.0f;
    #pragma unroll
    for (int i = 0; i < 64; i++) {
        float xi = x[i];
        aq += xi * QL[j * 65 + i];
        ak += xi * KL[j * 65 + i];
        av += xi * VL[j * 65 + i];
    }
    q[(size_t)s * 64 + j] = aq;
    k[(size_t)s * 64 + j] = ak;
    v[(size_t)s * 64 + j] = av;
}

// ---------------- generic 64->64 BN ReLU -> C head (wave per s) ----------------

__global__ __launch_bounds__(256) void k_head(
    const float* __restrict__ in,
    const float* __restrict__ W1, const float* __restrict__ b1,
    const float* __restrict__ g, const float* __restrict__ be,
    const float* __restrict__ W2, const float* __restrict__ b2,
    float* __restrict__ out, int C)
{
    __shared__ float W1L[64 * 65];
    __shared__ float W2L[20 * 65];
    __shared__ float b1L[64], sL[64], beL[64], b2L[20];
    __shared__ float hbuf[4][64];
    int tid = threadIdx.x;
    for (int idx = tid; idx < 4096; idx += 256) W1L[(idx >> 6) * 65 + (idx & 63)] = W1[idx];
    for (int idx = tid; idx < C * 64; idx += 256) W2L[(idx >> 6) * 65 + (idx & 63)] = W2[idx];
    if (tid < 64) { b1L[tid] = b1[tid]; sL[tid] = g[tid] * rsqrtf(1.0001f); beL[tid] = be[tid]; }
    if (tid < C) b2L[tid] = b2[tid];
    __syncthreads();
    int w = tid >> 6, lane = tid & 63;
    int s = blockIdx.x * 4 + w;
    bool act = s < S_;
    float h = 0.0f;
    if (act) {
        const float* x = in + (size_t)s * 64;
        float a = b1L[lane];
        #pragma unroll
        for (int i = 0; i < 64; i++) a += x[i] * W1L[lane * 65 + i];
        a = a * sL[lane] + beL[lane];
        h = a > 0.0f ? a : 0.0f;
    }
    hbuf[w][lane] = h;
    __syncthreads();
    if (act && lane < C) {
        float a = b2L[lane];
        #pragma unroll
        for (int j = 0; j < 64; j++) a += hbuf[w][j] * W2L[lane * 65 + j];
        out[(size_t)s * C + lane] = a;
    }
}

// ---------------- pos MLP per edge, scatter into CSR order ----------------

__global__ __launch_bounds__(256) void k_pos(
    const int* __restrict__ eu, const int* __restrict__ ev,
    const int* __restrict__ rank, const float* __restrict__ ctr,
    const float* __restrict__ pw1, const float* __restrict__ pb1,
    const float* __restrict__ pw2, const float* __restrict__ pb2,
    float* __restrict__ posv)
{
    __shared__ float PW1[48], PB1[16], PW2[16];
    __shared__ float PB2;
    int tid = threadIdx.x;
    if (tid < 48) PW1[tid] = pw1[tid];
    if (tid < 16) { PB1[tid] = pb1[tid]; PW2[tid] = pw2[tid]; }
    if (tid == 0) PB2 = pb2[0];
    __syncthreads();
    int e = blockIdx.x * 256 + tid;
    if (e >= E_) return;
    int u = eu[e], w = ev[e];
    float dx = ctr[u * 3]     - ctr[w * 3];
    float dy = ctr[u * 3 + 1] - ctr[w * 3 + 1];
    float dz = ctr[u * 3 + 2] - ctr[w * 3 + 2];
    float pos = PB2;
    #pragma unroll
    for (int hh = 0; hh < 16; hh++) {
        float a = PB1[hh] + dx * PW1[hh * 3] + dy * PW1[hh * 3 + 1] + dz * PW1[hh * 3 + 2];
        pos += (a > 0.0f ? a : 0.0f) * PW2[hh];
    }
    posv[rank[e]] = pos;
}

// ---------------- fused: aff (coalesced k-row dot) + softmax + weighted v scatter ----------------
// wave per segment, lane = dim. q-row loaded once; each k/v row is ONE coalesced 256B wave load.

__global__ __launch_bounds__(256) void k_attn(
    const int* __restrict__ start, const int* __restrict__ list,
    const int* __restrict__ evs, const float* __restrict__ posv,
    const float* __restrict__ q, const float* __restrict__ k,
    const float* __restrict__ v, const float* __restrict__ ecc,
    float* __restrict__ affs, float* __restrict__ soft, float* __restrict__ featb)
{
    int t = blockIdx.x * 256 + threadIdx.x;
    int s = t >> 6, lane = t & 63;
    if (s >= S_) return;
    int beg = start[s], end = start[s + 1];
    float qv = q[(size_t)s * 64 + lane];

    // pass 1: dot products (4 edges in flight), aff in CSR order, running max
    float m = -3.0e38f;
    int r = beg;
    for (; r + 4 <= end; r += 4) {
        int e0 = evs[r], e1 = evs[r + 1], e2 = evs[r + 2], e3 = evs[r + 3];
        float p0 = qv * k[(size_t)e0 * 64 + lane];
        float p1 = qv * k[(size_t)e1 * 64 + lane];
        float p2 = qv * k[(size_t)e2 * 64 + lane];
        float p3 = qv * k[(size_t)e3 * 64 + lane];
        #pragma unroll
        for (int o = 32; o; o >>= 1) {
            p0 += __shfl_xor(p0, o, 64);
            p1 += __shfl_xor(p1, o, 64);
            p2 += __shfl_xor(p2, o, 64);
            p3 += __shfl_xor(p3, o, 64);
        }
        float a0 = p0 * 0.125f * posv[r];
        float a1 = p1 * 0.125f * posv[r + 1];
        float a2 = p2 * 0.125f * posv[r + 2];
        float a3 = p3 * 0.125f * posv[r + 3];
        m = fmaxf(m, fmaxf(fmaxf(a0, a1), fmaxf(a2, a3)));
        if (lane < 4) {
            float av = lane == 0 ? a0 : lane == 1 ? a1 : lane == 2 ? a2 : a3;
            affs[r + lane] = av;
        }
    }
    for (; r < end; r++) {
        float p = qv * k[(size_t)evs[r] * 64 + lane];
        #pragma unroll
        for (int o = 32; o; o >>= 1) p += __shfl_xor(p, o, 64);
        float a = p * 0.125f * posv[r];
        m = fmaxf(m, a);
        if (lane == 0) affs[r] = a;
    }
    // m is wave-uniform (all lanes saw identical aff values)

    // pass 2: sum of exp (coalesced strided read)
    float tot = 0.0f;
    for (int i = beg + lane; i < end; i += 64) tot += __expf(affs[i] - m);
    #pragma unroll
    for (int o = 32; o; o >>= 1) tot += __shfl_xor(tot, o, 64);
    float inv = tot > 0.0f ? 1.0f / tot : 0.0f;

    // pass 3: weighted v gather (coalesced rows), soft scatter to original edge order
    float res = 0.0f;
    int i = beg;
    for (; i + 4 <= end; i += 4) {
        float a0 = affs[i], a1 = affs[i + 1], a2 = affs[i + 2], a3 = affs[i + 3];
        int   e0 = evs[i],  e1 = evs[i + 1],  e2 = evs[i + 2],  e3 = evs[i + 3];
        float s0 = __expf(a0 - m) * inv;
        float s1 = __expf(a1 - m) * inv;
        float s2 = __expf(a2 - m) * inv;
        float s3 = __expf(a3 - m) * inv;
        float v0 = v[(size_t)e0 * 64 + lane];
        float v1 = v[(size_t)e1 * 64 + lane];
        float v2 = v[(size_t)e2 * 64 + lane];
        float v3 = v[(size_t)e3 * 64 + lane];
        res += s0 * v0; res += s1 * v1; res += s2 * v2; res += s3 * v3;
        if (lane < 4) {
            float sv = lane == 0 ? s0 : lane == 1 ? s1 : lane == 2 ? s2 : s3;
            soft[list[i + lane]] = sv;
        }
    }
    for (; i < end; i++) {
        float sf = __expf(affs[i] - m) * inv;
        res += sf * v[(size_t)evs[i] * 64 + lane];
        if (lane == 0) soft[list[i]] = sf;
    }
    featb[(size_t)s * 64 + lane] = ecc[(size_t)s * 64 + lane] + res;
}

// ---------------- launch ----------------

extern "C" void kernel_launch(void* const* d_in, const int* in_sizes, int n_in,
                              void* d_out, int out_size, void* d_ws, size_t ws_size,
                              hipStream_t stream) {
    const float* output_feats = (const float*)d_in[0];
    const int*   input_map    = (const int*)d_in[1];
    const int*   superpoint   = (const int*)d_in[2];
    const float* ctr          = (const float*)d_in[3];
    const int*   edge_u       = (const int*)d_in[4];
    const int*   edge_v       = (const int*)d_in[5];
    const float* W_ecc        = (const float*)d_in[6];
    const float* lin_W1 = (const float*)d_in[7];
    const float* lin_b1 = (const float*)d_in[8];
    const float* lin_g  = (const float*)d_in[9];
    const float* lin_be = (const float*)d_in[10];
    const float* lin_W2 = (const float*)d_in[11];
    const float* lin_b2 = (const float*)d_in[12];
    const float* pos_W1 = (const float*)d_in[43];
    const float* pos_b1 = (const float*)d_in[44];
    const float* pos_W2 = (const float*)d_in[45];
    const float* pos_b2 = (const float*)d_in[46];
    const float* Wq     = (const float*)d_in[47];
    const float* Wk     = (const float*)d_in[48];
    const float* Wv     = (const float*)d_in[49];

    float* out = (float*)d_out;
    float* o_sem    = out;                    // [NP,20]
    float* o_spsem  = out + 30000000;         // [S,20]
    float* o_spoff  = out + 31000000;         // [S,3]
    float* o_spocc  = out + 31150000;         // [S]
    float* o_spsize = out + 31200000;         // [S]
    float* o_soft   = out + 31250000;         // [E]
    float* o_spdisc = out + 32850000;         // [S,7]

    // workspace layout
    char* base = (char*)d_ws;
    size_t off = 0;
    auto alloc = [&](size_t bytes) -> char* {
        char* p = base + off;
        off = (off + bytes + 255) & ~(size_t)255;
        return p;
    };
    int*   pt_cnt   = (int*)alloc(S_ * 4);
    int*   pt_start = (int*)alloc((S_ + 1) * 4);
    int*   pt_cur   = (int*)alloc(S_ * 4);
    int*   vidx     = (int*)alloc((size_t)NP_ * 4);
    int*   e_cnt    = (int*)alloc(S_ * 4);
    int*   e_start  = (int*)alloc((S_ + 1) * 4);
    int*   e_cur    = (int*)alloc(S_ * 4);
    int*   e_list   = (int*)alloc((size_t)E_ * 4);
    int*   e_vs     = (int*)alloc((size_t)E_ * 4);
    int*   e_rank   = (int*)alloc((size_t)E_ * 4);
    float* affs     = (float*)alloc((size_t)E_ * 4);
    float* posv     = (float*)alloc((size_t)E_ * 4);
    float* emb      = (float*)alloc((size_t)S_ * 32 * 4);
    float* ecc      = (float*)alloc((size_t)S_ * 64 * 4);
    float* qb       = (float*)alloc((size_t)S_ * 64 * 4);
    float* kb       = (float*)alloc((size_t)S_ * 64 * 4);
    float* vb       = (float*)alloc((size_t)S_ * 64 * 4);
    float* featb    = qb;  // safe overlay: wave s reads q-row s before writing featb-row s

    k_zero<<<(S_ + 255) / 256, 256, 0, stream>>>(pt_cnt, pt_cur, e_cnt, e_cur, S_);
    k_hist<<<(NP_ + 255) / 256, 256, 0, stream>>>(superpoint, pt_cnt, NP_);
    k_hist<<<(E_ + 255) / 256, 256, 0, stream>>>(edge_u, e_cnt, E_);
    k_scan<<<1, 1024, 0, stream>>>(pt_cnt, pt_start, S_);
    k_scan<<<1, 1024, 0, stream>>>(e_cnt, e_start, S_);
    k_fill_pts<<<(NP_ + 255) / 256, 256, 0, stream>>>(superpoint, input_map, pt_start, pt_cur, vidx, NP_);
    k_fill_edges<<<(E_ + 255) / 256, 256, 0, stream>>>(edge_u, edge_v, e_start, e_cur, e_list, e_vs, e_rank, E_);
    k_point_head<<<(NP_ + 255) / 256, 256, 0, stream>>>(
        output_feats, input_map, lin_W1, lin_b1, lin_g, lin_be, lin_W2, lin_b2, o_sem, NP_);
    k_mean<<<(S_ * 32) / 256, 256, 0, stream>>>(output_feats, vidx, pt_start, emb);
    k_ecc<<<S_ / 4, 256, 0, stream>>>(emb, W_ecc, ecc);
    k_qkv<<<S_ / 4, 256, 0, stream>>>(ecc, Wq, Wk, Wv, qb, kb, vb);
    k_head<<<S_ / 4, 256, 0, stream>>>(ecc, (const float*)d_in[13], (const float*)d_in[14],
        (const float*)d_in[15], (const float*)d_in[16], (const float*)d_in[17], (const float*)d_in[18],
        o_spsem, 20);
    k_head<<<S_ / 4, 256, 0, stream>>>(ecc, (const float*)d_in[19], (const float*)d_in[20],
        (const float*)d_in[21], (const float*)d_in[22], (const float*)d_in[23], (const float*)d_in[24],
        o_spoff, 3);
    k_head<<<S_ / 4, 256, 0, stream>>>(ecc, (const float*)d_in[25], (const float*)d_in[26],
        (const float*)d_in[27], (const float*)d_in[28], (const float*)d_in[29], (const float*)d_in[30],
        o_spocc, 1);
    k_head<<<S_ / 4, 256, 0, stream>>>(ecc, (const float*)d_in[31], (const float*)d_in[32],
        (const float*)d_in[33], (const float*)d_in[34], (const float*)d_in[35], (const float*)d_in[36],
        o_spsize, 1);
    k_pos<<<(E_ + 255) / 256, 256, 0, stream>>>(
        edge_u, edge_v, e_rank, ctr, pos_W1, pos_b1, pos_W2, pos_b2, posv);
    k_attn<<<S_ / 4, 256, 0, stream>>>(e_start, e_list, e_vs, posv, qb, kb, vb, ecc,
        affs, o_soft, featb);
    k_head<<<S_ / 4, 256, 0, stream>>>(featb, (const float*)d_in[37], (const float*)d_in[38],
        (const float*)d_in[39], (const float*)d_in[40], (const float*)d_in[41], (const float*)d_in[42],
        o_spdisc, 7);
}